// Round 2
// baseline (589.767 us; speedup 1.0000x reference)
//
#include <hip/hip_runtime.h>

// Problem constants (setup_inputs is fixed: N=4, Lq=6400, C=256, H=W=80)
#define NB    4
#define LQ    6400
#define CC    256
#define HH    80
#define WW    80
#define HWSZ  (HH*WW)        // 6400
#define RTOT  (NB*LQ)        // 25600 rows
#define HEADS 8
#define PTS   4
#define HD    32
#define HID   1024

typedef __attribute__((ext_vector_type(8))) short bf16x8;   // 8 bf16 = 4 VGPRs
typedef __attribute__((ext_vector_type(4))) float f32x4;

__device__ __forceinline__ float bf2f(unsigned short u) {
    unsigned int i = ((unsigned int)u) << 16;
    float f; __builtin_memcpy(&f, &i, 4); return f;
}
__device__ __forceinline__ unsigned short f2bf(float f) {
    unsigned int i; __builtin_memcpy(&i, &f, 4);
    unsigned int r = i + 0x7fffu + ((i >> 16) & 1u);   // RNE
    return (unsigned short)(r >> 16);
}

// ---------------- transpose + convert: Bt_bf16[n*K + k] = B_f32[k*N + n] ----------------
__global__ void transpose_cvt_k(const float* __restrict__ B,
                                unsigned short* __restrict__ Bt, int K, int N) {
    int idx = blockIdx.x * 256 + threadIdx.x;
    if (idx < K * N) {
        int n = idx / K;
        int k = idx - n * K;
        Bt[idx] = f2bf(B[k * N + n]);
    }
}

// ---------------- layernorm over C=256: fp32 in -> bf16 out; 1 wave/row, 4 rows/block ----
__global__ void ln_k(const float* __restrict__ x,
                     const float* __restrict__ w,
                     const float* __restrict__ b,
                     unsigned short* __restrict__ y) {
    int row  = blockIdx.x * 4 + (threadIdx.x >> 6);
    int lane = threadIdx.x & 63;
    const float* xr = x + (size_t)row * CC + lane * 4;
    float4 u = *(const float4*)xr;
    float s  = u.x + u.y + u.z + u.w;
    float s2 = u.x*u.x + u.y*u.y + u.z*u.z + u.w*u.w;
    #pragma unroll
    for (int m = 1; m < 64; m <<= 1) {
        s  += __shfl_xor(s,  m);
        s2 += __shfl_xor(s2, m);
    }
    float mean = s * (1.0f / CC);
    float var  = s2 * (1.0f / CC) - mean * mean;
    float rstd = rsqrtf(fmaxf(var, 0.0f) + 1e-5f);
    float4 uw = *(const float4*)(w + lane * 4);
    float4 ub = *(const float4*)(b + lane * 4);
    ushort4 o;
    o.x = f2bf((u.x - mean) * rstd * uw.x + ub.x);
    o.y = f2bf((u.y - mean) * rstd * uw.y + ub.y);
    o.z = f2bf((u.z - mean) * rstd * uw.z + ub.z);
    o.w = f2bf((u.w - mean) * rstd * uw.w + ub.w);
    *(ushort4*)(y + (size_t)row * CC + lane * 4) = o;
}

// ---------------- GEMM: C[M,N] = A[M,K] @ Bt[N,K]^T + bias ----------------
// EPI: 0=none, 1=gelu(exact), 2=add fp32 residual (stride N)
// AF32: A is fp32 (convert inline); else A is bf16.
// OF32: store fp32; else store bf16.
// block = 256 thr = 4 waves; wave tile 16x64; block tile 64x64.
// gfx950 16x16x32_bf16 layouts: A[m=lane&15][k=quad*8+j]; B identically from Bt;
// D: row = quad*4 + r, col = lane&15.
template<int EPI, bool AF32, bool OF32>
__global__ void gemm_k(const void* __restrict__ A_,
                       const unsigned short* __restrict__ Bt,
                       const float* __restrict__ bias,
                       const float* __restrict__ res,
                       void* __restrict__ Cout_,
                       int M, int N, int K) {
    int lane = threadIdx.x & 63;
    int wave = threadIdx.x >> 6;
    int quad = lane >> 4;
    int l16  = lane & 15;
    int m0 = blockIdx.x * 64 + wave * 16;
    int n0 = blockIdx.y * 64;

    f32x4 acc[4];
    #pragma unroll
    for (int s = 0; s < 4; ++s) acc[s] = (f32x4){0.f, 0.f, 0.f, 0.f};

    bool act[4];
    #pragma unroll
    for (int s = 0; s < 4; ++s) act[s] = (n0 + s * 16) < N;   // wave-uniform

    const float*          Af = (const float*)A_ + (size_t)(m0 + l16) * K + quad * 8;
    const unsigned short* Ab = (const unsigned short*)A_ + (size_t)(m0 + l16) * K + quad * 8;
    const unsigned short* Bp = Bt + (size_t)(n0 + l16) * K + quad * 8;

    for (int k0 = 0; k0 < K; k0 += 32) {
        bf16x8 af;
        if (AF32) {
            float4 a0 = *(const float4*)(Af + k0);
            float4 a1 = *(const float4*)(Af + k0 + 4);
            af[0] = (short)f2bf(a0.x); af[1] = (short)f2bf(a0.y);
            af[2] = (short)f2bf(a0.z); af[3] = (short)f2bf(a0.w);
            af[4] = (short)f2bf(a1.x); af[5] = (short)f2bf(a1.y);
            af[6] = (short)f2bf(a1.z); af[7] = (short)f2bf(a1.w);
        } else {
            af = *(const bf16x8*)(Ab + k0);
        }
        #pragma unroll
        for (int s = 0; s < 4; ++s) {
            if (act[s]) {
                bf16x8 bfv = *(const bf16x8*)(Bp + (size_t)(s * 16) * K + k0);
                acc[s] = __builtin_amdgcn_mfma_f32_16x16x32_bf16(af, bfv, acc[s], 0, 0, 0);
            }
        }
    }

    #pragma unroll
    for (int s = 0; s < 4; ++s) {
        if (!act[s]) continue;
        int n = n0 + s * 16 + l16;
        float bv = bias[n];
        #pragma unroll
        for (int r = 0; r < 4; ++r) {
            int row = m0 + quad * 4 + r;
            float val = acc[s][r] + bv;
            if (EPI == 1) val = 0.5f * val * (1.0f + erff(val * 0.70710678118654752f));
            if (EPI == 2) val += res[(size_t)row * N + n];
            if (OF32) ((float*)Cout_)[(size_t)row * N + n] = val;
            else      ((unsigned short*)Cout_)[(size_t)row * N + n] = f2bf(val);
        }
    }
}

// ---------------- deformable sampling ----------------
// one block per query row; thread = head (t>>5) x channel (t&31)
__global__ void sample_k(const unsigned short* __restrict__ v,    // (NB, HW, C) bf16
                         const float* __restrict__ ref,           // (NB, Lq, 2) fp32
                         const unsigned short* __restrict__ off,  // (R, 64) bf16 (h,p,2)
                         const unsigned short* __restrict__ awl,  // (R, 32) bf16 logits
                         unsigned short* __restrict__ samp) {     // (R, 256) bf16
    int row = blockIdx.x;
    int h = threadIdx.x >> 5;
    int c = threadIdx.x & 31;
    int n = row / LQ;

    float refx = ref[row * 2 + 0];
    float refy = ref[row * 2 + 1];

    // softmax over 4 points for this head (redundant across the 32 channel threads)
    float l0 = bf2f(awl[row * 32 + h * 4 + 0]);
    float l1 = bf2f(awl[row * 32 + h * 4 + 1]);
    float l2 = bf2f(awl[row * 32 + h * 4 + 2]);
    float l3 = bf2f(awl[row * 32 + h * 4 + 3]);
    float mx = fmaxf(fmaxf(l0, l1), fmaxf(l2, l3));
    float e0 = expf(l0 - mx), e1 = expf(l1 - mx), e2 = expf(l2 - mx), e3 = expf(l3 - mx);
    float inv = 1.0f / (e0 + e1 + e2 + e3);
    float wp[4] = {e0 * inv, e1 * inv, e2 * inv, e3 * inv};

    const unsigned short* vbase = v + (size_t)n * HWSZ * CC + h * HD + c;

    float acc = 0.0f;
    #pragma unroll
    for (int p = 0; p < 4; ++p) {
        float ox = bf2f(off[row * 64 + (h * 4 + p) * 2 + 0]);
        float oy = bf2f(off[row * 64 + (h * 4 + p) * 2 + 1]);
        float gx = (refx + ox * (1.0f / WW)) * WW - 0.5f;
        float gy = (refy + oy * (1.0f / HH)) * HH - 0.5f;
        float fx = floorf(gx), fy = floorf(gy);
        float wx = gx - fx, wy = gy - fy;
        int x0 = (int)fx, y0 = (int)fy;
        float w00 = (1.f - wx) * (1.f - wy);
        float w10 = wx * (1.f - wy);
        float w01 = (1.f - wx) * wy;
        float w11 = wx * wy;
        float sv = 0.0f;
        if ((unsigned)x0     < WW && (unsigned)y0     < HH) sv += w00 * bf2f(vbase[(size_t)(y0 * WW + x0) * CC]);
        if ((unsigned)(x0+1) < WW && (unsigned)y0     < HH) sv += w10 * bf2f(vbase[(size_t)(y0 * WW + x0 + 1) * CC]);
        if ((unsigned)x0     < WW && (unsigned)(y0+1) < HH) sv += w01 * bf2f(vbase[(size_t)((y0 + 1) * WW + x0) * CC]);
        if ((unsigned)(x0+1) < WW && (unsigned)(y0+1) < HH) sv += w11 * bf2f(vbase[(size_t)((y0 + 1) * WW + x0 + 1) * CC]);
        acc += wp[p] * sv;
    }
    samp[(size_t)row * CC + h * HD + c] = f2bf(acc);
}

extern "C" void kernel_launch(void* const* d_in, const int* in_sizes, int n_in,
                              void* d_out, int out_size, void* d_ws, size_t ws_size,
                              hipStream_t stream) {
    const float* x     = (const float*)d_in[0];
    const float* ref   = (const float*)d_in[1];
    const float* value = (const float*)d_in[2];
    // d_in[3]=H, d_in[4]=W (int scalars; fixed 80x80 — unused)
    const float* ln1w  = (const float*)d_in[5];
    const float* ln1b  = (const float*)d_in[6];
    const float* ln2w  = (const float*)d_in[7];
    const float* ln2b  = (const float*)d_in[8];
    const float* Wv    = (const float*)d_in[9];
    const float* bv    = (const float*)d_in[10];
    const float* Woff  = (const float*)d_in[11];
    const float* boff  = (const float*)d_in[12];
    const float* Wa    = (const float*)d_in[13];
    const float* ba    = (const float*)d_in[14];
    const float* Wout  = (const float*)d_in[15];
    const float* bout  = (const float*)d_in[16];
    const float* W1    = (const float*)d_in[17];
    const float* b1    = (const float*)d_in[18];
    const float* W2    = (const float*)d_in[19];
    const float* b2    = (const float*)d_in[20];

    // ---- workspace layout (bytes) ----
    char* ws = (char*)d_ws;
    unsigned short* wt_v  = (unsigned short*)(ws + 0);          // 131072 B
    unsigned short* wt_of = (unsigned short*)(ws + 131072);     // 32768
    unsigned short* wt_a  = (unsigned short*)(ws + 163840);     // 16384
    unsigned short* wt_o  = (unsigned short*)(ws + 180224);     // 131072
    unsigned short* wt_1  = (unsigned short*)(ws + 311296);     // 524288
    unsigned short* wt_2  = (unsigned short*)(ws + 835584);     // 524288 -> 1359872
    float*          x2_f  = (float*)         (ws + 1441792);    // 26,214,400 -> 27,656,192 (live to end)
    unsigned short* h_b   = (unsigned short*)(ws + 27656192);   // 13,107,200 -> 40,763,392 (LN2 out)
    // dead-pool region, later overlaid by h1 (52,428,800 B @ 40,763,392 -> 93,192,192)
    unsigned short* xn_b  = (unsigned short*)(ws + 40763392);   // 13,107,200
    unsigned short* v_b   = (unsigned short*)(ws + 53870592);   // 13,107,200
    unsigned short* off_b = (unsigned short*)(ws + 66977792);   // 3,276,800
    unsigned short* awl_b = (unsigned short*)(ws + 70254592);   // 1,638,400
    unsigned short* smp_b = (unsigned short*)(ws + 71892992);   // 13,107,200 -> 85,000,192
    unsigned short* h1_b  = (unsigned short*)(ws + 40763392);   // overlays pool (all dead by MLP-up)

    // pre-transpose+convert all weight matrices: Bt[n*K+k] = bf16(B[k*N+n])
    transpose_cvt_k<<<(256*256 + 255) / 256, 256, 0, stream>>>(Wv,   wt_v,  256, 256);
    transpose_cvt_k<<<(256*64  + 255) / 256, 256, 0, stream>>>(Woff, wt_of, 256, 64);
    transpose_cvt_k<<<(256*32  + 255) / 256, 256, 0, stream>>>(Wa,   wt_a,  256, 32);
    transpose_cvt_k<<<(256*256 + 255) / 256, 256, 0, stream>>>(Wout, wt_o,  256, 256);
    transpose_cvt_k<<<(256*1024+ 255) / 256, 256, 0, stream>>>(W1,   wt_1,  256, 1024);
    transpose_cvt_k<<<(256*1024+ 255) / 256, 256, 0, stream>>>(W2,   wt_2,  1024, 256);

    // LN1: fp32 x -> bf16 xn
    ln_k<<<RTOT / 4, 256, 0, stream>>>(x, ln1w, ln1b, xn_b);

    dim3 blk(256);
    // value projection (fp32 A inline-converted) -> bf16 v
    gemm_k<0, true,  false><<<dim3(RTOT / 64, 4),  blk, 0, stream>>>(value, wt_v,  bv,   nullptr, v_b,   RTOT, 256,  256);
    // offsets + attention logits
    gemm_k<0, false, false><<<dim3(RTOT / 64, 1),  blk, 0, stream>>>(xn_b,  wt_of, boff, nullptr, off_b, RTOT, 64,   256);
    gemm_k<0, false, false><<<dim3(RTOT / 64, 1),  blk, 0, stream>>>(xn_b,  wt_a,  ba,   nullptr, awl_b, RTOT, 32,   256);
    // deformable bilinear sampling + softmax-weighted sum over points
    sample_k<<<RTOT, 256, 0, stream>>>(v_b, ref, off_b, awl_b, smp_b);
    // output projection + residual(x) -> fp32 x2
    gemm_k<2, false, true ><<<dim3(RTOT / 64, 4),  blk, 0, stream>>>(smp_b, wt_o,  bout, x,       x2_f,  RTOT, 256,  256);
    // LN2: fp32 x2 -> bf16 h
    ln_k<<<RTOT / 4, 256, 0, stream>>>(x2_f, ln2w, ln2b, h_b);
    // MLP up + exact GELU -> bf16 h1
    gemm_k<1, false, false><<<dim3(RTOT / 64, 16), blk, 0, stream>>>(h_b,   wt_1,  b1,   nullptr, h1_b,  RTOT, 1024, 256);
    // MLP down + residual(x2) -> fp32 out
    gemm_k<2, false, true ><<<dim3(RTOT / 64, 4),  blk, 0, stream>>>(h1_b,  wt_2,  b2,   x2_f, (float*)d_out, RTOT, 256, 1024);
}

// Round 3
// 359.786 us; speedup vs baseline: 1.6392x; 1.6392x over previous
//
#include <hip/hip_runtime.h>

// Problem constants (setup_inputs fixed: N=4, Lq=6400, C=256, H=W=80)
#define NB    4
#define LQ    6400
#define CC    256
#define HH    80
#define WW    80
#define HWSZ  (HH*WW)
#define RTOT  (NB*LQ)        // 25600 rows
#define HID   1024

typedef __attribute__((ext_vector_type(8))) short bf16x8;   // 8 bf16 = 4 VGPRs
typedef __attribute__((ext_vector_type(4))) float f32x4;

__device__ __forceinline__ float bf2f(unsigned short u) {
    unsigned int i = ((unsigned int)u) << 16;
    float f; __builtin_memcpy(&f, &i, 4); return f;
}
__device__ __forceinline__ unsigned short f2bf(float f) {
    unsigned int i; __builtin_memcpy(&i, &f, 4);
    unsigned int r = i + 0x7fffu + ((i >> 16) & 1u);   // RNE
    return (unsigned short)(r >> 16);
}

// ---------------- fp32 -> bf16 convert (4 elems/thread) ----------------
__global__ void cvt_k(const float* __restrict__ in, unsigned short* __restrict__ out, int n4) {
    int i = blockIdx.x * 256 + threadIdx.x;
    if (i < n4) {
        float4 u = ((const float4*)in)[i];
        ushort4 o;
        o.x = f2bf(u.x); o.y = f2bf(u.y); o.z = f2bf(u.z); o.w = f2bf(u.w);
        ((ushort4*)out)[i] = o;
    }
}

// ---------------- transpose + convert: Bt_bf16[n*K + k] = B_f32[k*N + n] ----------------
__global__ void transpose_cvt_k(const float* __restrict__ B,
                                unsigned short* __restrict__ Bt, int K, int N) {
    int idx = blockIdx.x * 256 + threadIdx.x;
    if (idx < K * N) {
        int n = idx / K;
        int k = idx - n * K;
        Bt[idx] = f2bf(B[k * N + n]);
    }
}

// ---------------- concat boff(64) + ba(32) into one fp32 bias[96] ----------------
__global__ void bias_cat_k(const float* __restrict__ boff, const float* __restrict__ ba,
                           float* __restrict__ out) {
    int i = threadIdx.x;
    if (i < 64) out[i] = boff[i];
    else if (i < 96) out[i] = ba[i - 64];
}

// ---------------- layernorm over C=256: fp32 in -> bf16 out; 1 wave/row ----------------
__global__ void ln_k(const float* __restrict__ x,
                     const float* __restrict__ w,
                     const float* __restrict__ b,
                     unsigned short* __restrict__ y) {
    int row  = blockIdx.x * 4 + (threadIdx.x >> 6);
    int lane = threadIdx.x & 63;
    const float* xr = x + (size_t)row * CC + lane * 4;
    float4 u = *(const float4*)xr;
    float s  = u.x + u.y + u.z + u.w;
    float s2 = u.x*u.x + u.y*u.y + u.z*u.z + u.w*u.w;
    #pragma unroll
    for (int m = 1; m < 64; m <<= 1) {
        s  += __shfl_xor(s,  m);
        s2 += __shfl_xor(s2, m);
    }
    float mean = s * (1.0f / CC);
    float var  = s2 * (1.0f / CC) - mean * mean;
    float rstd = rsqrtf(fmaxf(var, 0.0f) + 1e-5f);
    float4 uw = *(const float4*)(w + lane * 4);
    float4 ub = *(const float4*)(b + lane * 4);
    ushort4 o;
    o.x = f2bf((u.x - mean) * rstd * uw.x + ub.x);
    o.y = f2bf((u.y - mean) * rstd * uw.y + ub.y);
    o.z = f2bf((u.z - mean) * rstd * uw.z + ub.z);
    o.w = f2bf((u.w - mean) * rstd * uw.w + ub.w);
    *(ushort4*)(y + (size_t)row * CC + lane * 4) = o;
}

// ---------------- tiled GEMM: C[M,Nv] = A[M,K] @ Bt[Npad,K]^T + bias ----------------
// m97-structure: 128x128 block tile, 4 waves (2x2 of 64x64), BK=32,
// global_load_lds width-16 staging, ds_read_b128 fragments, 16 MFMA/wave/ktile.
// EPI: 0=none, 1=gelu(exact), 2=add fp32 residual (stride Nv). OF32: fp32 out.
// Requires M%128==0, K%32==0, grid.y = Npad/128, Nv%16==0, Bt has Npad rows.
template<int EPI, bool OF32>
__global__ __launch_bounds__(256) void gemm_t(const unsigned short* __restrict__ A,
                                              const unsigned short* __restrict__ Bt,
                                              const float* __restrict__ bias,
                                              const float* __restrict__ res,
                                              void* __restrict__ Cout_,
                                              int M, int Nv, int K) {
    __shared__ unsigned short Als[128 * 32];
    __shared__ unsigned short Bls[128 * 32];
    int lane = threadIdx.x & 63;
    int wave = threadIdx.x >> 6;
    int quad = lane >> 4;
    int l16  = lane & 15;
    int m0 = blockIdx.x * 128;
    int n0 = blockIdx.y * 128;
    int wm = (wave & 1) * 64;
    int wn = (wave >> 1) * 64;

    f32x4 acc[4][4];
    #pragma unroll
    for (int i = 0; i < 4; ++i)
        #pragma unroll
        for (int j = 0; j < 4; ++j)
            acc[i][j] = (f32x4){0.f, 0.f, 0.f, 0.f};

    // staging: wave w stages rows [w*32, w*32+32) of each 128x32 tile,
    // 2 instrs of 16 rows; lane i -> LDS base + i*16B (row i/4, col (i%4)*8)
    int srow = lane >> 2;            // 0..15
    int scol = (lane & 3) * 8;       // element offset in row
    const unsigned short* Ag = A  + (size_t)(m0 + wave * 32 + srow) * K + scol;
    const unsigned short* Bg = Bt + (size_t)(n0 + wave * 32 + srow) * K + scol;
    unsigned short* Alp = &Als[wave * 1024];
    unsigned short* Blp = &Bls[wave * 1024];

    for (int k0 = 0; k0 < K; k0 += 32) {
        __syncthreads();             // previous tile's reads complete
        #pragma unroll
        for (int t = 0; t < 2; ++t) {
            __builtin_amdgcn_global_load_lds(
                (const __attribute__((address_space(1))) void*)(Ag + (size_t)t * 16 * K + k0),
                (__attribute__((address_space(3))) void*)(Alp + t * 512), 16, 0, 0);
            __builtin_amdgcn_global_load_lds(
                (const __attribute__((address_space(1))) void*)(Bg + (size_t)t * 16 * K + k0),
                (__attribute__((address_space(3))) void*)(Blp + t * 512), 16, 0, 0);
        }
        __builtin_amdgcn_s_waitcnt(0);
        __syncthreads();

        bf16x8 af[4], bfr[4];
        #pragma unroll
        for (int i = 0; i < 4; ++i)
            af[i] = *(const bf16x8*)&Als[(wm + i * 16 + l16) * 32 + quad * 8];
        #pragma unroll
        for (int j = 0; j < 4; ++j)
            bfr[j] = *(const bf16x8*)&Bls[(wn + j * 16 + l16) * 32 + quad * 8];
        #pragma unroll
        for (int i = 0; i < 4; ++i)
            #pragma unroll
            for (int j = 0; j < 4; ++j)
                acc[i][j] = __builtin_amdgcn_mfma_f32_16x16x32_bf16(af[i], bfr[j], acc[i][j], 0, 0, 0);
    }

    // epilogue: D row = quad*4+r (A side), col = l16 (B side)
    #pragma unroll
    for (int j = 0; j < 4; ++j) {
        int cbase = n0 + wn + j * 16;
        if (cbase >= Nv) continue;                 // wave-uniform (Nv%16==0)
        int col = cbase + l16;
        float bv = bias[col];
        #pragma unroll
        for (int i = 0; i < 4; ++i) {
            #pragma unroll
            for (int r = 0; r < 4; ++r) {
                int row = m0 + wm + i * 16 + quad * 4 + r;
                float val = acc[i][j][r] + bv;
                if (EPI == 1) val = 0.5f * val * (1.0f + erff(val * 0.70710678118654752f));
                if (EPI == 2) val += res[(size_t)row * Nv + col];
                if (OF32) ((float*)Cout_)[(size_t)row * Nv + col] = val;
                else      ((unsigned short*)Cout_)[(size_t)row * Nv + col] = f2bf(val);
            }
        }
    }
}

// ---------------- deformable sampling ----------------
// one block per query row; thread = head (t>>5) x channel (t&31)
// oa: (R, 96) bf16 = [off(h,p,2) 64 | awl(h,p) 32]
__global__ void sample_k(const unsigned short* __restrict__ v,    // (NB, HW, C) bf16
                         const float* __restrict__ ref,           // (NB, Lq, 2) fp32
                         const unsigned short* __restrict__ oa,
                         unsigned short* __restrict__ samp) {     // (R, 256) bf16
    int row = blockIdx.x;
    int h = threadIdx.x >> 5;
    int c = threadIdx.x & 31;
    int n = row / LQ;

    float refx = ref[row * 2 + 0];
    float refy = ref[row * 2 + 1];

    const unsigned short* oar = oa + (size_t)row * 96;
    float l0 = bf2f(oar[64 + h * 4 + 0]);
    float l1 = bf2f(oar[64 + h * 4 + 1]);
    float l2 = bf2f(oar[64 + h * 4 + 2]);
    float l3 = bf2f(oar[64 + h * 4 + 3]);
    float mx = fmaxf(fmaxf(l0, l1), fmaxf(l2, l3));
    float e0 = expf(l0 - mx), e1 = expf(l1 - mx), e2 = expf(l2 - mx), e3 = expf(l3 - mx);
    float inv = 1.0f / (e0 + e1 + e2 + e3);
    float wp[4] = {e0 * inv, e1 * inv, e2 * inv, e3 * inv};

    const unsigned short* vbase = v + (size_t)n * HWSZ * CC + h * 32 + c;

    float acc = 0.0f;
    #pragma unroll
    for (int p = 0; p < 4; ++p) {
        float ox = bf2f(oar[(h * 4 + p) * 2 + 0]);
        float oy = bf2f(oar[(h * 4 + p) * 2 + 1]);
        float gx = (refx + ox * (1.0f / WW)) * WW - 0.5f;
        float gy = (refy + oy * (1.0f / HH)) * HH - 0.5f;
        float fx = floorf(gx), fy = floorf(gy);
        float wx = gx - fx, wy = gy - fy;
        int x0 = (int)fx, y0 = (int)fy;
        float w00 = (1.f - wx) * (1.f - wy);
        float w10 = wx * (1.f - wy);
        float w01 = (1.f - wx) * wy;
        float w11 = wx * wy;
        float sv = 0.0f;
        if ((unsigned)x0     < WW && (unsigned)y0     < HH) sv += w00 * bf2f(vbase[(size_t)(y0 * WW + x0) * CC]);
        if ((unsigned)(x0+1) < WW && (unsigned)y0     < HH) sv += w10 * bf2f(vbase[(size_t)(y0 * WW + x0 + 1) * CC]);
        if ((unsigned)x0     < WW && (unsigned)(y0+1) < HH) sv += w01 * bf2f(vbase[(size_t)((y0 + 1) * WW + x0) * CC]);
        if ((unsigned)(x0+1) < WW && (unsigned)(y0+1) < HH) sv += w11 * bf2f(vbase[(size_t)((y0 + 1) * WW + x0 + 1) * CC]);
        acc += wp[p] * sv;
    }
    samp[(size_t)row * CC + h * 32 + c] = f2bf(acc);
}

extern "C" void kernel_launch(void* const* d_in, const int* in_sizes, int n_in,
                              void* d_out, int out_size, void* d_ws, size_t ws_size,
                              hipStream_t stream) {
    const float* x     = (const float*)d_in[0];
    const float* ref   = (const float*)d_in[1];
    const float* value = (const float*)d_in[2];
    const float* ln1w  = (const float*)d_in[5];
    const float* ln1b  = (const float*)d_in[6];
    const float* ln2w  = (const float*)d_in[7];
    const float* ln2b  = (const float*)d_in[8];
    const float* Wv    = (const float*)d_in[9];
    const float* bv    = (const float*)d_in[10];
    const float* Woff  = (const float*)d_in[11];
    const float* boff  = (const float*)d_in[12];
    const float* Wa    = (const float*)d_in[13];
    const float* ba    = (const float*)d_in[14];
    const float* Wout  = (const float*)d_in[15];
    const float* bout  = (const float*)d_in[16];
    const float* W1    = (const float*)d_in[17];
    const float* b1    = (const float*)d_in[18];
    const float* W2    = (const float*)d_in[19];
    const float* b2    = (const float*)d_in[20];

    // ---- workspace layout (bytes), peak 93,127,168 ----
    char* ws = (char*)d_ws;
    unsigned short* wt_v  = (unsigned short*)(ws + 0);          // 131072
    unsigned short* wt_o  = (unsigned short*)(ws + 131072);     // 131072
    unsigned short* wt_1  = (unsigned short*)(ws + 262144);     // 524288
    unsigned short* wt_2  = (unsigned short*)(ws + 786432);     // 524288
    unsigned short* wt_oa = (unsigned short*)(ws + 1310720);    // 65536 (128 rows x 256, rows 96..127 garbage)
    float*          b_oa  = (float*)         (ws + 1376256);    // 512
    float*          x2_f  = (float*)         (ws + 1376768);    // 26,214,400 (live to end)
    unsigned short* h_b   = (unsigned short*)(ws + 27591168);   // 13,107,200 (LN2 out)
    // pool @ 40,698,368 (52.43 MB), overlaid by h1 after Wout GEMM
    unsigned short* val_b = (unsigned short*)(ws + 40698368);   // 13,107,200 (dead after value GEMM)
    unsigned short* smp_b = (unsigned short*)(ws + 40698368);   // overlays val_b (written at sample)
    unsigned short* xn_b  = (unsigned short*)(ws + 53805568);   // 13,107,200
    unsigned short* v_b   = (unsigned short*)(ws + 66912768);   // 13,107,200
    unsigned short* oa_b  = (unsigned short*)(ws + 80019968);   // 4,915,200 -> 84,935,168
    unsigned short* h1_b  = (unsigned short*)(ws + 40698368);   // 52,428,800 -> 93,127,168

    // weight prep
    transpose_cvt_k<<<(256*256 + 255) / 256, 256, 0, stream>>>(Wv,   wt_v,         256, 256);
    transpose_cvt_k<<<(256*256 + 255) / 256, 256, 0, stream>>>(Wout, wt_o,         256, 256);
    transpose_cvt_k<<<(256*1024+ 255) / 256, 256, 0, stream>>>(W1,   wt_1,         256, 1024);
    transpose_cvt_k<<<(256*1024+ 255) / 256, 256, 0, stream>>>(W2,   wt_2,         1024, 256);
    transpose_cvt_k<<<(256*64  + 255) / 256, 256, 0, stream>>>(Woff, wt_oa,        256, 64);
    transpose_cvt_k<<<(256*32  + 255) / 256, 256, 0, stream>>>(Wa,   wt_oa + 64*256, 256, 32);
    bias_cat_k<<<1, 128, 0, stream>>>(boff, ba, b_oa);

    // value fp32 -> bf16
    cvt_k<<<(RTOT*CC/4 + 255) / 256, 256, 0, stream>>>(value, val_b, RTOT*CC/4);
    // LN1: x -> xn
    ln_k<<<RTOT / 4, 256, 0, stream>>>(x, ln1w, ln1b, xn_b);

    dim3 blk(256);
    // value projection -> v_b
    gemm_t<0, false><<<dim3(RTOT/128, 2), blk, 0, stream>>>(val_b, wt_v,  bv,   nullptr, v_b,  RTOT, 256,  256);
    // fused offsets + attention logits -> oa_b (N valid 96, padded 128)
    gemm_t<0, false><<<dim3(RTOT/128, 1), blk, 0, stream>>>(xn_b,  wt_oa, b_oa, nullptr, oa_b, RTOT, 96,   256);
    // deformable sampling -> smp_b
    sample_k<<<RTOT, 256, 0, stream>>>(v_b, ref, oa_b, smp_b);
    // output projection + residual(x) -> x2 (fp32)
    gemm_t<2, true ><<<dim3(RTOT/128, 2), blk, 0, stream>>>(smp_b, wt_o,  bout, x,       x2_f, RTOT, 256,  256);
    // LN2: x2 -> h
    ln_k<<<RTOT / 4, 256, 0, stream>>>(x2_f, ln2w, ln2b, h_b);
    // MLP up + exact GELU -> h1
    gemm_t<1, false><<<dim3(RTOT/128, 8), blk, 0, stream>>>(h_b,   wt_1,  b1,   nullptr, h1_b, RTOT, 1024, 256);
    // MLP down + residual(x2) -> out (fp32)
    gemm_t<2, true ><<<dim3(RTOT/128, 2), blk, 0, stream>>>(h1_b,  wt_2,  b2,   x2_f, (float*)d_out, RTOT, 256, 1024);
}

// Round 4
// 293.170 us; speedup vs baseline: 2.0117x; 1.2272x over previous
//
#include <hip/hip_runtime.h>

// Problem constants (setup_inputs fixed: N=4, Lq=6400, C=256, H=W=80)
#define NB    4
#define LQ    6400
#define CC    256
#define HH    80
#define WW    80
#define HWSZ  (HH*WW)
#define RTOT  (NB*LQ)        // 25600 rows
#define HID   1024

typedef __attribute__((ext_vector_type(8))) short bf16x8;   // 8 bf16 = 4 VGPRs
typedef __attribute__((ext_vector_type(4))) float f32x4;

__device__ __forceinline__ float bf2f(unsigned short u) {
    unsigned int i = ((unsigned int)u) << 16;
    float f; __builtin_memcpy(&f, &i, 4); return f;
}
__device__ __forceinline__ unsigned short f2bf(float f) {
    unsigned int i; __builtin_memcpy(&i, &f, 4);
    unsigned int r = i + 0x7fffu + ((i >> 16) & 1u);   // RNE
    return (unsigned short)(r >> 16);
}

// ---------------- fp32 -> bf16 convert (4 elems/thread) ----------------
__global__ void cvt_k(const float* __restrict__ in, unsigned short* __restrict__ out, int n4) {
    int i = blockIdx.x * 256 + threadIdx.x;
    if (i < n4) {
        float4 u = ((const float4*)in)[i];
        ushort4 o;
        o.x = f2bf(u.x); o.y = f2bf(u.y); o.z = f2bf(u.z); o.w = f2bf(u.w);
        ((ushort4*)out)[i] = o;
    }
}

// ---------------- transpose + convert: Bt_bf16[n*K + k] = B_f32[k*N + n] ----------------
__global__ void transpose_cvt_k(const float* __restrict__ B,
                                unsigned short* __restrict__ Bt, int K, int N) {
    int idx = blockIdx.x * 256 + threadIdx.x;
    if (idx < K * N) {
        int n = idx / K;
        int k = idx - n * K;
        Bt[idx] = f2bf(B[k * N + n]);
    }
}

// ---------------- concat boff(64) + ba(32) into one fp32 bias[96] ----------------
__global__ void bias_cat_k(const float* __restrict__ boff, const float* __restrict__ ba,
                           float* __restrict__ out) {
    int i = threadIdx.x;
    if (i < 64) out[i] = boff[i];
    else if (i < 96) out[i] = ba[i - 64];
}

// ---------------- layernorm over C=256: fp32 in -> bf16 out; 1 wave/row ----------------
__global__ void ln_k(const float* __restrict__ x,
                     const float* __restrict__ w,
                     const float* __restrict__ b,
                     unsigned short* __restrict__ y) {
    int row  = blockIdx.x * 4 + (threadIdx.x >> 6);
    int lane = threadIdx.x & 63;
    const float* xr = x + (size_t)row * CC + lane * 4;
    float4 u = *(const float4*)xr;
    float s  = u.x + u.y + u.z + u.w;
    float s2 = u.x*u.x + u.y*u.y + u.z*u.z + u.w*u.w;
    #pragma unroll
    for (int m = 1; m < 64; m <<= 1) {
        s  += __shfl_xor(s,  m);
        s2 += __shfl_xor(s2, m);
    }
    float mean = s * (1.0f / CC);
    float var  = s2 * (1.0f / CC) - mean * mean;
    float rstd = rsqrtf(fmaxf(var, 0.0f) + 1e-5f);
    float4 uw = *(const float4*)(w + lane * 4);
    float4 ub = *(const float4*)(b + lane * 4);
    ushort4 o;
    o.x = f2bf((u.x - mean) * rstd * uw.x + ub.x);
    o.y = f2bf((u.y - mean) * rstd * uw.y + ub.y);
    o.z = f2bf((u.z - mean) * rstd * uw.z + ub.z);
    o.w = f2bf((u.w - mean) * rstd * uw.w + ub.w);
    *(ushort4*)(y + (size_t)row * CC + lane * 4) = o;
}

// ---------------- tiled GEMM (m97 structure) ----------------
template<int EPI, bool OF32>
__global__ __launch_bounds__(256) void gemm_t(const unsigned short* __restrict__ A,
                                              const unsigned short* __restrict__ Bt,
                                              const float* __restrict__ bias,
                                              const float* __restrict__ res,
                                              void* __restrict__ Cout_,
                                              int M, int Nv, int K) {
    __shared__ unsigned short Als[128 * 32];
    __shared__ unsigned short Bls[128 * 32];
    int lane = threadIdx.x & 63;
    int wave = threadIdx.x >> 6;
    int quad = lane >> 4;
    int l16  = lane & 15;
    int m0 = blockIdx.x * 128;
    int n0 = blockIdx.y * 128;
    int wm = (wave & 1) * 64;
    int wn = (wave >> 1) * 64;

    f32x4 acc[4][4];
    #pragma unroll
    for (int i = 0; i < 4; ++i)
        #pragma unroll
        for (int j = 0; j < 4; ++j)
            acc[i][j] = (f32x4){0.f, 0.f, 0.f, 0.f};

    int srow = lane >> 2;
    int scol = (lane & 3) * 8;
    const unsigned short* Ag = A  + (size_t)(m0 + wave * 32 + srow) * K + scol;
    const unsigned short* Bg = Bt + (size_t)(n0 + wave * 32 + srow) * K + scol;
    unsigned short* Alp = &Als[wave * 1024];
    unsigned short* Blp = &Bls[wave * 1024];

    for (int k0 = 0; k0 < K; k0 += 32) {
        __syncthreads();
        #pragma unroll
        for (int t = 0; t < 2; ++t) {
            __builtin_amdgcn_global_load_lds(
                (const __attribute__((address_space(1))) void*)(Ag + (size_t)t * 16 * K + k0),
                (__attribute__((address_space(3))) void*)(Alp + t * 512), 16, 0, 0);
            __builtin_amdgcn_global_load_lds(
                (const __attribute__((address_space(1))) void*)(Bg + (size_t)t * 16 * K + k0),
                (__attribute__((address_space(3))) void*)(Blp + t * 512), 16, 0, 0);
        }
        __builtin_amdgcn_s_waitcnt(0);
        __syncthreads();

        bf16x8 af[4], bfr[4];
        #pragma unroll
        for (int i = 0; i < 4; ++i)
            af[i] = *(const bf16x8*)&Als[(wm + i * 16 + l16) * 32 + quad * 8];
        #pragma unroll
        for (int j = 0; j < 4; ++j)
            bfr[j] = *(const bf16x8*)&Bls[(wn + j * 16 + l16) * 32 + quad * 8];
        #pragma unroll
        for (int i = 0; i < 4; ++i)
            #pragma unroll
            for (int j = 0; j < 4; ++j)
                acc[i][j] = __builtin_amdgcn_mfma_f32_16x16x32_bf16(af[i], bfr[j], acc[i][j], 0, 0, 0);
    }

    #pragma unroll
    for (int j = 0; j < 4; ++j) {
        int cbase = n0 + wn + j * 16;
        if (cbase >= Nv) continue;
        int col = cbase + l16;
        float bv = bias[col];
        #pragma unroll
        for (int i = 0; i < 4; ++i) {
            #pragma unroll
            for (int r = 0; r < 4; ++r) {
                int row = m0 + wm + i * 16 + quad * 4 + r;
                float val = acc[i][j][r] + bv;
                if (EPI == 1) val = 0.5f * val * (1.0f + erff(val * 0.70710678118654752f));
                if (EPI == 2) val += res[(size_t)row * Nv + col];
                if (OF32) ((float*)Cout_)[(size_t)row * Nv + col] = val;
                else      ((unsigned short*)Cout_)[(size_t)row * Nv + col] = f2bf(val);
            }
        }
    }
}

// ---------------- deformable sampling, two-phase ----------------
// Block = 256 threads, 8 queries (block-uniform batch since LQ%8==0).
// Phase 1: thread = (q,h,p) -> combined corner weights (softmax x bilinear x valid)
//          + clamped flat indices into LDS.
// Phase 2: thread = (q, h, cg): 8 contiguous channels, 16x bf16x8 gathers.
__global__ __launch_bounds__(256) void sample_k(
        const unsigned short* __restrict__ v,    // (NB, HW, C) bf16
        const float* __restrict__ ref,           // (NB, Lq, 2) fp32
        const unsigned short* __restrict__ oa,   // (R, 96) bf16 = [off 64 | awl 32]
        unsigned short* __restrict__ samp) {     // (R, 256) bf16
    __shared__ int4   sidx[256];
    __shared__ float4 sw[256];

    int t = threadIdx.x;
    int row0 = blockIdx.x * 8;
    int n = blockIdx.x / (LQ / 8);               // batch, block-uniform

    // ---- phase 1 ----
    {
        int q = t >> 5;              // 0..7
        int h = (t >> 2) & 7;        // 0..7
        int p = t & 3;               // 0..3
        int row = row0 + q;
        float refx = ref[row * 2 + 0];
        float refy = ref[row * 2 + 1];
        const unsigned short* oar = oa + (size_t)row * 96;
        float ox = bf2f(oar[(h * 4 + p) * 2 + 0]);
        float oy = bf2f(oar[(h * 4 + p) * 2 + 1]);
        float l  = bf2f(oar[64 + h * 4 + p]);
        // softmax across the 4 p-lanes (t bits 0..1)
        float m = fmaxf(l, __shfl_xor(l, 1));
        m = fmaxf(m, __shfl_xor(m, 2));
        float e = __expf(l - m);
        float s = e + __shfl_xor(e, 1);
        s = s + __shfl_xor(s, 2);
        float wp = e / s;

        float gx = (refx + ox * (1.0f / WW)) * WW - 0.5f;
        float gy = (refy + oy * (1.0f / HH)) * HH - 0.5f;
        float fx = floorf(gx), fy = floorf(gy);
        float wx = gx - fx, wy = gy - fy;
        int x0 = (int)fx, y0 = (int)fy;
        int x1 = x0 + 1, y1 = y0 + 1;
        bool vx0 = (unsigned)x0 < WW, vx1 = (unsigned)x1 < WW;
        bool vy0 = (unsigned)y0 < HH, vy1 = (unsigned)y1 < HH;
        float w00 = (vx0 && vy0) ? wp * (1.f - wx) * (1.f - wy) : 0.f;
        float w10 = (vx1 && vy0) ? wp * wx * (1.f - wy)         : 0.f;
        float w01 = (vx0 && vy1) ? wp * (1.f - wx) * wy         : 0.f;
        float w11 = (vx1 && vy1) ? wp * wx * wy                 : 0.f;
        int cx0 = min(max(x0, 0), WW - 1), cx1 = min(max(x1, 0), WW - 1);
        int cy0 = min(max(y0, 0), HH - 1), cy1 = min(max(y1, 0), HH - 1);
        sidx[t] = (int4){cy0 * WW + cx0, cy0 * WW + cx1, cy1 * WW + cx0, cy1 * WW + cx1};
        sw[t]   = (float4){w00, w10, w01, w11};
    }
    __syncthreads();

    // ---- phase 2 ----
    int q  = t >> 5;
    int sub = t & 31;
    int h  = sub >> 2;
    int cg = sub & 3;
    int row = row0 + q;
    const unsigned short* base = v + (size_t)n * HWSZ * CC + h * 32 + cg * 8;

    float acc[8];
    #pragma unroll
    for (int j = 0; j < 8; ++j) acc[j] = 0.f;

    #pragma unroll
    for (int p = 0; p < 4; ++p) {
        int e = ((q * 8 + h) * 4) + p;
        int4   I = sidx[e];
        float4 Wt = sw[e];
        const int* Ip = (const int*)&I;
        const float* Wp = (const float*)&Wt;
        #pragma unroll
        for (int c = 0; c < 4; ++c) {
            bf16x8 u = *(const bf16x8*)(base + (size_t)Ip[c] * CC);
            float wgt = Wp[c];
            #pragma unroll
            for (int j = 0; j < 8; ++j)
                acc[j] += wgt * bf2f((unsigned short)u[j]);
        }
    }

    bf16x8 o;
    #pragma unroll
    for (int j = 0; j < 8; ++j) o[j] = (short)f2bf(acc[j]);
    *(bf16x8*)(samp + (size_t)row * CC + h * 32 + cg * 8) = o;
}

extern "C" void kernel_launch(void* const* d_in, const int* in_sizes, int n_in,
                              void* d_out, int out_size, void* d_ws, size_t ws_size,
                              hipStream_t stream) {
    const float* x     = (const float*)d_in[0];
    const float* ref   = (const float*)d_in[1];
    const float* value = (const float*)d_in[2];
    const float* ln1w  = (const float*)d_in[5];
    const float* ln1b  = (const float*)d_in[6];
    const float* ln2w  = (const float*)d_in[7];
    const float* ln2b  = (const float*)d_in[8];
    const float* Wv    = (const float*)d_in[9];
    const float* bv    = (const float*)d_in[10];
    const float* Woff  = (const float*)d_in[11];
    const float* boff  = (const float*)d_in[12];
    const float* Wa    = (const float*)d_in[13];
    const float* ba    = (const float*)d_in[14];
    const float* Wout  = (const float*)d_in[15];
    const float* bout  = (const float*)d_in[16];
    const float* W1    = (const float*)d_in[17];
    const float* b1    = (const float*)d_in[18];
    const float* W2    = (const float*)d_in[19];
    const float* b2    = (const float*)d_in[20];

    // ---- workspace layout (bytes), peak 93,127,168 ----
    char* ws = (char*)d_ws;
    unsigned short* wt_v  = (unsigned short*)(ws + 0);          // 131072
    unsigned short* wt_o  = (unsigned short*)(ws + 131072);     // 131072
    unsigned short* wt_1  = (unsigned short*)(ws + 262144);     // 524288
    unsigned short* wt_2  = (unsigned short*)(ws + 786432);     // 524288
    unsigned short* wt_oa = (unsigned short*)(ws + 1310720);    // 65536 (128 rows x 256)
    float*          b_oa  = (float*)         (ws + 1376256);    // 512
    float*          x2_f  = (float*)         (ws + 1376768);    // 26,214,400 (live to end)
    unsigned short* h_b   = (unsigned short*)(ws + 27591168);   // 13,107,200 (LN2 out)
    unsigned short* val_b = (unsigned short*)(ws + 40698368);   // 13,107,200 (dead after value GEMM)
    unsigned short* smp_b = (unsigned short*)(ws + 40698368);   // overlays val_b
    unsigned short* xn_b  = (unsigned short*)(ws + 53805568);   // 13,107,200
    unsigned short* v_b   = (unsigned short*)(ws + 66912768);   // 13,107,200
    unsigned short* oa_b  = (unsigned short*)(ws + 80019968);   // 4,915,200
    unsigned short* h1_b  = (unsigned short*)(ws + 40698368);   // 52,428,800 -> 93,127,168

    // weight prep
    transpose_cvt_k<<<(256*256 + 255) / 256, 256, 0, stream>>>(Wv,   wt_v,           256, 256);
    transpose_cvt_k<<<(256*256 + 255) / 256, 256, 0, stream>>>(Wout, wt_o,           256, 256);
    transpose_cvt_k<<<(256*1024+ 255) / 256, 256, 0, stream>>>(W1,   wt_1,           256, 1024);
    transpose_cvt_k<<<(256*1024+ 255) / 256, 256, 0, stream>>>(W2,   wt_2,           1024, 256);
    transpose_cvt_k<<<(256*64  + 255) / 256, 256, 0, stream>>>(Woff, wt_oa,          256, 64);
    transpose_cvt_k<<<(256*32  + 255) / 256, 256, 0, stream>>>(Wa,   wt_oa + 64*256, 256, 32);
    bias_cat_k<<<1, 128, 0, stream>>>(boff, ba, b_oa);

    cvt_k<<<(RTOT*CC/4 + 255) / 256, 256, 0, stream>>>(value, val_b, RTOT*CC/4);
    ln_k<<<RTOT / 4, 256, 0, stream>>>(x, ln1w, ln1b, xn_b);

    dim3 blk(256);
    gemm_t<0, false><<<dim3(RTOT/128, 2), blk, 0, stream>>>(val_b, wt_v,  bv,   nullptr, v_b,  RTOT, 256,  256);
    gemm_t<0, false><<<dim3(RTOT/128, 1), blk, 0, stream>>>(xn_b,  wt_oa, b_oa, nullptr, oa_b, RTOT, 96,   256);
    sample_k<<<RTOT / 8, 256, 0, stream>>>(v_b, ref, oa_b, smp_b);
    gemm_t<2, true ><<<dim3(RTOT/128, 2), blk, 0, stream>>>(smp_b, wt_o,  bout, x,       x2_f, RTOT, 256,  256);
    ln_k<<<RTOT / 4, 256, 0, stream>>>(x2_f, ln2w, ln2b, h_b);
    gemm_t<1, false><<<dim3(RTOT/128, 8), blk, 0, stream>>>(h_b,   wt_1,  b1,   nullptr, h1_b, RTOT, 1024, 256);
    gemm_t<2, true ><<<dim3(RTOT/128, 2), blk, 0, stream>>>(h1_b,  wt_2,  b2,   x2_f, (float*)d_out, RTOT, 256, 1024);
}

// Round 5
// 285.258 us; speedup vs baseline: 2.0675x; 1.0277x over previous
//
#include <hip/hip_runtime.h>

// Problem constants (setup_inputs fixed: N=4, Lq=6400, C=256, H=W=80)
#define NB    4
#define LQ    6400
#define CC    256
#define HH    80
#define WW    80
#define HWSZ  (HH*WW)
#define RTOT  (NB*LQ)        // 25600 rows
#define HID   1024

typedef __attribute__((ext_vector_type(8))) short bf16x8;   // 8 bf16 = 4 VGPRs
typedef __attribute__((ext_vector_type(4))) float f32x4;

__device__ __forceinline__ float bf2f(unsigned short u) {
    unsigned int i = ((unsigned int)u) << 16;
    float f; __builtin_memcpy(&f, &i, 4); return f;
}
__device__ __forceinline__ unsigned short f2bf(float f) {
    unsigned int i; __builtin_memcpy(&i, &f, 4);
    unsigned int r = i + 0x7fffu + ((i >> 16) & 1u);   // RNE
    return (unsigned short)(r >> 16);
}

// ---------------- fp32 -> bf16 convert (4 elems/thread) ----------------
__global__ void cvt_k(const float* __restrict__ in, unsigned short* __restrict__ out, int n4) {
    int i = blockIdx.x * 256 + threadIdx.x;
    if (i < n4) {
        float4 u = ((const float4*)in)[i];
        ushort4 o;
        o.x = f2bf(u.x); o.y = f2bf(u.y); o.z = f2bf(u.z); o.w = f2bf(u.w);
        ((ushort4*)out)[i] = o;
    }
}

// ---------------- transpose + convert: Bt_bf16[n*K + k] = B_f32[k*N + n] ----------------
__global__ void transpose_cvt_k(const float* __restrict__ B,
                                unsigned short* __restrict__ Bt, int K, int N) {
    int idx = blockIdx.x * 256 + threadIdx.x;
    if (idx < K * N) {
        int n = idx / K;
        int k = idx - n * K;
        Bt[idx] = f2bf(B[k * N + n]);
    }
}

// ---------------- fragment-major weight swizzle ----------------
// dst group g (8 bf16 each): n = g%N, kq = g/N, kbase = (kq>>2)*32 + (kq&3)*8
// dst[g*8 + j] = bf16(src[(kbase+j)*N + n])   -- the exact LDS/VGPR image an
// A-fragment load wants: lane(l16,quad) reads group (kb*4+quad)*N + n contiguously.
__global__ void swizzle_k(const float* __restrict__ src, unsigned short* __restrict__ dst,
                          int K, int N) {
    int g = blockIdx.x * 256 + threadIdx.x;
    if (g >= (K / 8) * N) return;
    int n  = g % N;
    int kq = g / N;
    int kbase = (kq >> 2) * 32 + (kq & 3) * 8;
    unsigned short* d = dst + (size_t)g * 8;
    #pragma unroll
    for (int j = 0; j < 8; ++j)
        d[j] = f2bf(src[(size_t)(kbase + j) * N + n]);
}

// ---------------- concat boff(64) + ba(32) into one fp32 bias[96] ----------------
__global__ void bias_cat_k(const float* __restrict__ boff, const float* __restrict__ ba,
                           float* __restrict__ out) {
    int i = threadIdx.x;
    if (i < 64) out[i] = boff[i];
    else if (i < 96) out[i] = ba[i - 64];
}

// ---------------- layernorm over C=256: fp32 in -> bf16 out; 1 wave/row ----------------
__global__ void ln_k(const float* __restrict__ x,
                     const float* __restrict__ w,
                     const float* __restrict__ b,
                     unsigned short* __restrict__ y) {
    int row  = blockIdx.x * 4 + (threadIdx.x >> 6);
    int lane = threadIdx.x & 63;
    const float* xr = x + (size_t)row * CC + lane * 4;
    float4 u = *(const float4*)xr;
    float s  = u.x + u.y + u.z + u.w;
    float s2 = u.x*u.x + u.y*u.y + u.z*u.z + u.w*u.w;
    #pragma unroll
    for (int m = 1; m < 64; m <<= 1) {
        s  += __shfl_xor(s,  m);
        s2 += __shfl_xor(s2, m);
    }
    float mean = s * (1.0f / CC);
    float var  = s2 * (1.0f / CC) - mean * mean;
    float rstd = rsqrtf(fmaxf(var, 0.0f) + 1e-5f);
    float4 uw = *(const float4*)(w + lane * 4);
    float4 ub = *(const float4*)(b + lane * 4);
    ushort4 o;
    o.x = f2bf((u.x - mean) * rstd * uw.x + ub.x);
    o.y = f2bf((u.y - mean) * rstd * uw.y + ub.y);
    o.z = f2bf((u.z - mean) * rstd * uw.z + ub.z);
    o.w = f2bf((u.w - mean) * rstd * uw.w + ub.w);
    *(ushort4*)(y + (size_t)row * CC + lane * 4) = o;
}

// ---------------- tiled GEMM (m97 structure) ----------------
template<int EPI, bool OF32>
__global__ __launch_bounds__(256) void gemm_t(const unsigned short* __restrict__ A,
                                              const unsigned short* __restrict__ Bt,
                                              const float* __restrict__ bias,
                                              const float* __restrict__ res,
                                              void* __restrict__ Cout_,
                                              int M, int Nv, int K) {
    __shared__ unsigned short Als[128 * 32];
    __shared__ unsigned short Bls[128 * 32];
    int lane = threadIdx.x & 63;
    int wave = threadIdx.x >> 6;
    int quad = lane >> 4;
    int l16  = lane & 15;
    int m0 = blockIdx.x * 128;
    int n0 = blockIdx.y * 128;
    int wm = (wave & 1) * 64;
    int wn = (wave >> 1) * 64;

    f32x4 acc[4][4];
    #pragma unroll
    for (int i = 0; i < 4; ++i)
        #pragma unroll
        for (int j = 0; j < 4; ++j)
            acc[i][j] = (f32x4){0.f, 0.f, 0.f, 0.f};

    int srow = lane >> 2;
    int scol = (lane & 3) * 8;
    const unsigned short* Ag = A  + (size_t)(m0 + wave * 32 + srow) * K + scol;
    const unsigned short* Bg = Bt + (size_t)(n0 + wave * 32 + srow) * K + scol;
    unsigned short* Alp = &Als[wave * 1024];
    unsigned short* Blp = &Bls[wave * 1024];

    for (int k0 = 0; k0 < K; k0 += 32) {
        __syncthreads();
        #pragma unroll
        for (int t = 0; t < 2; ++t) {
            __builtin_amdgcn_global_load_lds(
                (const __attribute__((address_space(1))) void*)(Ag + (size_t)t * 16 * K + k0),
                (__attribute__((address_space(3))) void*)(Alp + t * 512), 16, 0, 0);
            __builtin_amdgcn_global_load_lds(
                (const __attribute__((address_space(1))) void*)(Bg + (size_t)t * 16 * K + k0),
                (__attribute__((address_space(3))) void*)(Blp + t * 512), 16, 0, 0);
        }
        __builtin_amdgcn_s_waitcnt(0);
        __syncthreads();

        bf16x8 af[4], bfr[4];
        #pragma unroll
        for (int i = 0; i < 4; ++i)
            af[i] = *(const bf16x8*)&Als[(wm + i * 16 + l16) * 32 + quad * 8];
        #pragma unroll
        for (int j = 0; j < 4; ++j)
            bfr[j] = *(const bf16x8*)&Bls[(wn + j * 16 + l16) * 32 + quad * 8];
        #pragma unroll
        for (int i = 0; i < 4; ++i)
            #pragma unroll
            for (int j = 0; j < 4; ++j)
                acc[i][j] = __builtin_amdgcn_mfma_f32_16x16x32_bf16(af[i], bfr[j], acc[i][j], 0, 0, 0);
    }

    #pragma unroll
    for (int j = 0; j < 4; ++j) {
        int cbase = n0 + wn + j * 16;
        if (cbase >= Nv) continue;
        int col = cbase + l16;
        float bv = bias[col];
        #pragma unroll
        for (int i = 0; i < 4; ++i) {
            #pragma unroll
            for (int r = 0; r < 4; ++r) {
                int row = m0 + wm + i * 16 + quad * 4 + r;
                float val = acc[i][j][r] + bv;
                if (EPI == 1) val = 0.5f * val * (1.0f + erff(val * 0.70710678118654752f));
                if (EPI == 2) val += res[(size_t)row * Nv + col];
                if (OF32) ((float*)Cout_)[(size_t)row * Nv + col] = val;
                else      ((unsigned short*)Cout_)[(size_t)row * Nv + col] = f2bf(val);
            }
        }
    }
}

// ---------------- deformable sampling, two-phase ----------------
__global__ __launch_bounds__(256) void sample_k(
        const unsigned short* __restrict__ v,    // (NB, HW, C) bf16
        const float* __restrict__ ref,           // (NB, Lq, 2) fp32
        const unsigned short* __restrict__ oa,   // (R, 96) bf16 = [off 64 | awl 32]
        unsigned short* __restrict__ samp) {     // (R, 256) bf16
    __shared__ int4   sidx[256];
    __shared__ float4 sw[256];

    int t = threadIdx.x;
    int row0 = blockIdx.x * 8;
    int n = blockIdx.x / (LQ / 8);

    {
        int q = t >> 5;
        int h = (t >> 2) & 7;
        int p = t & 3;
        int row = row0 + q;
        float refx = ref[row * 2 + 0];
        float refy = ref[row * 2 + 1];
        const unsigned short* oar = oa + (size_t)row * 96;
        float ox = bf2f(oar[(h * 4 + p) * 2 + 0]);
        float oy = bf2f(oar[(h * 4 + p) * 2 + 1]);
        float l  = bf2f(oar[64 + h * 4 + p]);
        float m = fmaxf(l, __shfl_xor(l, 1));
        m = fmaxf(m, __shfl_xor(m, 2));
        float e = __expf(l - m);
        float s = e + __shfl_xor(e, 1);
        s = s + __shfl_xor(s, 2);
        float wp = e / s;

        float gx = (refx + ox * (1.0f / WW)) * WW - 0.5f;
        float gy = (refy + oy * (1.0f / HH)) * HH - 0.5f;
        float fx = floorf(gx), fy = floorf(gy);
        float wx = gx - fx, wy = gy - fy;
        int x0 = (int)fx, y0 = (int)fy;
        int x1 = x0 + 1, y1 = y0 + 1;
        bool vx0 = (unsigned)x0 < WW, vx1 = (unsigned)x1 < WW;
        bool vy0 = (unsigned)y0 < HH, vy1 = (unsigned)y1 < HH;
        float w00 = (vx0 && vy0) ? wp * (1.f - wx) * (1.f - wy) : 0.f;
        float w10 = (vx1 && vy0) ? wp * wx * (1.f - wy)         : 0.f;
        float w01 = (vx0 && vy1) ? wp * (1.f - wx) * wy         : 0.f;
        float w11 = (vx1 && vy1) ? wp * wx * wy                 : 0.f;
        int cx0 = min(max(x0, 0), WW - 1), cx1 = min(max(x1, 0), WW - 1);
        int cy0 = min(max(y0, 0), HH - 1), cy1 = min(max(y1, 0), HH - 1);
        sidx[t] = (int4){cy0 * WW + cx0, cy0 * WW + cx1, cy1 * WW + cx0, cy1 * WW + cx1};
        sw[t]   = (float4){w00, w10, w01, w11};
    }
    __syncthreads();

    int q  = t >> 5;
    int sub = t & 31;
    int h  = sub >> 2;
    int cg = sub & 3;
    int row = row0 + q;
    const unsigned short* base = v + (size_t)n * HWSZ * CC + h * 32 + cg * 8;

    float acc[8];
    #pragma unroll
    for (int j = 0; j < 8; ++j) acc[j] = 0.f;

    #pragma unroll
    for (int p = 0; p < 4; ++p) {
        int e = ((q * 8 + h) * 4) + p;
        int4   I = sidx[e];
        float4 Wt = sw[e];
        const int* Ip = (const int*)&I;
        const float* Wp = (const float*)&Wt;
        #pragma unroll
        for (int c = 0; c < 4; ++c) {
            bf16x8 u = *(const bf16x8*)(base + (size_t)Ip[c] * CC);
            float wgt = Wp[c];
            #pragma unroll
            for (int j = 0; j < 8; ++j)
                acc[j] += wgt * bf2f((unsigned short)u[j]);
        }
    }

    bf16x8 o;
    #pragma unroll
    for (int j = 0; j < 8; ++j) o[j] = (short)f2bf(acc[j]);
    *(bf16x8*)(samp + (size_t)row * CC + h * 32 + cg * 8) = o;
}

// ---------------- fused MLP: out = x2 + (gelu(h@W1 + b1))@W2 + b2 ----------------
// Block = 64 rows, 256 thr (4 waves). Hidden 1024 in 8 chunks of 128.
// Stage1: mfma(A=W1frag, B=hfrag) -> D1[hidden=quad*4+r][qrow=l16]; gelu -> h1blob (LDS).
// Stage2: mfma(A=W2frag, B=h1frag) -> D2[c=quad*4+r][qrow=l16]; transpose via LDS; store.
// W1s/W2s are pre-swizzled fragment-major blobs (see swizzle_k).
__global__ __launch_bounds__(256) void mlp_k(
        const unsigned short* __restrict__ h,    // (R,256) bf16 row-major
        const unsigned short* __restrict__ w1s,  // swizzled (256x1024)
        const float* __restrict__ b1,
        const unsigned short* __restrict__ w2s,  // swizzled (1024x256)
        const float* __restrict__ b2,
        const float* __restrict__ x2,            // (R,256) fp32 residual
        float* __restrict__ out) {
    __shared__ char lds_raw[33280 + 16384];
    unsigned short* hblob  = (unsigned short*)lds_raw;            // [kq<32] stride 1040 B
    unsigned short* h1blob = (unsigned short*)(lds_raw + 33280);  // [kq2<16] stride 1024 B
    float* trans = (float*)lds_raw;                               // alias (epilogue only)

    int t = threadIdx.x;
    int lane = t & 63, wave = t >> 6;
    int quad = lane >> 4, l16 = lane & 15;
    int row0 = blockIdx.x * 64;
    int wc = wave * 64;

    // ---- stage h tile (64x256) into fragment-major padded blob ----
    {
        int kq = t & 31;
        int rb = t >> 5;
        #pragma unroll
        for (int i = 0; i < 8; ++i) {
            int r = i * 8 + rb;
            bf16x8 u = *(const bf16x8*)(h + (size_t)(row0 + r) * CC + kq * 8);
            *(bf16x8*)((char*)hblob + kq * 1040 + r * 16) = u;
        }
    }
    __syncthreads();

    f32x4 acc2[4][4];    // [ct][qt]: c = wc+ct*16+quad*4+r, qrow = qt*16+l16
    #pragma unroll
    for (int a = 0; a < 4; ++a)
        #pragma unroll
        for (int b = 0; b < 4; ++b)
            acc2[a][b] = (f32x4){0.f, 0.f, 0.f, 0.f};

    for (int hc = 0; hc < 8; ++hc) {
        // ---- stage 1: h1 chunk (hidden 128: this wave's 32) ----
        f32x4 acc1[2][4];   // [ht][qt]
        #pragma unroll
        for (int a = 0; a < 2; ++a)
            #pragma unroll
            for (int b = 0; b < 4; ++b)
                acc1[a][b] = (f32x4){0.f, 0.f, 0.f, 0.f};

        #pragma unroll
        for (int kb = 0; kb < 8; ++kb) {
            bf16x8 a1[2], b1f[4];
            #pragma unroll
            for (int ht = 0; ht < 2; ++ht) {
                int hh = hc * 128 + wave * 32 + ht * 16 + l16;
                a1[ht] = *(const bf16x8*)(w1s + ((size_t)(kb * 4 + quad) * 1024 + hh) * 8);
            }
            #pragma unroll
            for (int qt = 0; qt < 4; ++qt)
                b1f[qt] = *(const bf16x8*)((char*)hblob + (kb * 4 + quad) * 1040 + (qt * 16 + l16) * 16);
            #pragma unroll
            for (int ht = 0; ht < 2; ++ht)
                #pragma unroll
                for (int qt = 0; qt < 4; ++qt)
                    acc1[ht][qt] = __builtin_amdgcn_mfma_f32_16x16x32_bf16(a1[ht], b1f[qt], acc1[ht][qt], 0, 0, 0);
        }

        // bias + exact gelu + pack 4 bf16 -> h1blob (b64 writes, conflict-free)
        #pragma unroll
        for (int ht = 0; ht < 2; ++ht) {
            int hl = wave * 32 + ht * 16 + quad * 4;          // hidden local in chunk
            float4 bb = *(const float4*)(b1 + hc * 128 + hl);
            const float* bp = (const float*)&bb;
            #pragma unroll
            for (int qt = 0; qt < 4; ++qt) {
                unsigned long long pk = 0;
                #pragma unroll
                for (int r = 0; r < 4; ++r) {
                    float val = acc1[ht][qt][r] + bp[r];
                    val = 0.5f * val * (1.0f + erff(val * 0.70710678118654752f));
                    pk |= ((unsigned long long)f2bf(val)) << (16 * r);
                }
                int qrow = qt * 16 + l16;
                *(unsigned long long*)((char*)h1blob + (hl >> 3) * 1024 + qrow * 16 + (hl & 7) * 2) = pk;
            }
        }
        __syncthreads();

        // ---- stage 2: acc2 += gelu(h1_chunk) @ W2[chunk rows] ----
        #pragma unroll
        for (int k2 = 0; k2 < 4; ++k2) {
            int kb2 = hc * 4 + k2;
            bf16x8 a2[4], b2f[4];
            #pragma unroll
            for (int ct = 0; ct < 4; ++ct) {
                int cc = wc + ct * 16 + l16;
                a2[ct] = *(const bf16x8*)(w2s + ((size_t)(kb2 * 4 + quad) * 256 + cc) * 8);
            }
            #pragma unroll
            for (int qt = 0; qt < 4; ++qt)
                b2f[qt] = *(const bf16x8*)((char*)h1blob + (k2 * 4 + quad) * 1024 + (qt * 16 + l16) * 16);
            #pragma unroll
            for (int ct = 0; ct < 4; ++ct)
                #pragma unroll
                for (int qt = 0; qt < 4; ++qt)
                    acc2[ct][qt] = __builtin_amdgcn_mfma_f32_16x16x32_bf16(a2[ct], b2f[qt], acc2[ct][qt], 0, 0, 0);
        }
        __syncthreads();
    }

    // ---- epilogue: transpose D2 via LDS, add x2 + b2, coalesced store ----
    for (int p = 0; p < 2; ++p) {
        __syncthreads();
        #pragma unroll
        for (int qi = 0; qi < 2; ++qi) {
            int qt = p * 2 + qi;
            int qlocal = qt * 16 + l16 - p * 32;
            #pragma unroll
            for (int ct = 0; ct < 4; ++ct) {
                int c4 = (wc >> 2) + ct * 4 + quad;          // c/4 index, 0..63
                int c4s = c4 ^ (qlocal & 7);                 // bank swizzle
                *(f32x4*)(trans + qlocal * 260 + c4s * 4) = acc2[ct][qt];
            }
        }
        __syncthreads();
        int rr = t >> 3;
        int c4b = t & 7;
        #pragma unroll
        for (int i = 0; i < 8; ++i) {
            int c4 = i * 8 + c4b;
            int c4s = c4 ^ (rr & 7);
            f32x4 v = *(const f32x4*)(trans + rr * 260 + c4s * 4);
            int row = row0 + p * 32 + rr;
            int c = c4 * 4;
            float4 xv = *(const float4*)(x2 + (size_t)row * CC + c);
            float4 bb = *(const float4*)(b2 + c);
            float4 o;
            o.x = v[0] + xv.x + bb.x;
            o.y = v[1] + xv.y + bb.y;
            o.z = v[2] + xv.z + bb.z;
            o.w = v[3] + xv.w + bb.w;
            *(float4*)(out + (size_t)row * CC + c) = o;
        }
    }
}

extern "C" void kernel_launch(void* const* d_in, const int* in_sizes, int n_in,
                              void* d_out, int out_size, void* d_ws, size_t ws_size,
                              hipStream_t stream) {
    const float* x     = (const float*)d_in[0];
    const float* ref   = (const float*)d_in[1];
    const float* value = (const float*)d_in[2];
    const float* ln1w  = (const float*)d_in[5];
    const float* ln1b  = (const float*)d_in[6];
    const float* ln2w  = (const float*)d_in[7];
    const float* ln2b  = (const float*)d_in[8];
    const float* Wv    = (const float*)d_in[9];
    const float* bv    = (const float*)d_in[10];
    const float* Woff  = (const float*)d_in[11];
    const float* boff  = (const float*)d_in[12];
    const float* Wa    = (const float*)d_in[13];
    const float* ba    = (const float*)d_in[14];
    const float* Wout  = (const float*)d_in[15];
    const float* bout  = (const float*)d_in[16];
    const float* W1    = (const float*)d_in[17];
    const float* b1    = (const float*)d_in[18];
    const float* W2    = (const float*)d_in[19];
    const float* b2    = (const float*)d_in[20];

    // ---- workspace layout (bytes), peak 84,935,168 ----
    char* ws = (char*)d_ws;
    unsigned short* wt_v  = (unsigned short*)(ws + 0);          // 131072
    unsigned short* wt_o  = (unsigned short*)(ws + 131072);     // 131072
    unsigned short* w1s_b = (unsigned short*)(ws + 262144);     // 524288 (swizzled)
    unsigned short* w2s_b = (unsigned short*)(ws + 786432);     // 524288 (swizzled)
    unsigned short* wt_oa = (unsigned short*)(ws + 1310720);    // 65536
    float*          b_oa  = (float*)         (ws + 1376256);    // 512
    float*          x2_f  = (float*)         (ws + 1376768);    // 26,214,400 (live to end)
    unsigned short* h_b   = (unsigned short*)(ws + 27591168);   // 13,107,200 (LN2 out)
    unsigned short* val_b = (unsigned short*)(ws + 40698368);   // 13,107,200
    unsigned short* smp_b = (unsigned short*)(ws + 40698368);   // overlays val_b
    unsigned short* xn_b  = (unsigned short*)(ws + 53805568);   // 13,107,200
    unsigned short* v_b   = (unsigned short*)(ws + 66912768);   // 13,107,200
    unsigned short* oa_b  = (unsigned short*)(ws + 80019968);   // 4,915,200

    // weight prep
    transpose_cvt_k<<<(256*256 + 255) / 256, 256, 0, stream>>>(Wv,   wt_v,           256, 256);
    transpose_cvt_k<<<(256*256 + 255) / 256, 256, 0, stream>>>(Wout, wt_o,           256, 256);
    transpose_cvt_k<<<(256*64  + 255) / 256, 256, 0, stream>>>(Woff, wt_oa,          256, 64);
    transpose_cvt_k<<<(256*32  + 255) / 256, 256, 0, stream>>>(Wa,   wt_oa + 64*256, 256, 32);
    swizzle_k<<<128, 256, 0, stream>>>(W1, w1s_b, 256, 1024);
    swizzle_k<<<128, 256, 0, stream>>>(W2, w2s_b, 1024, 256);
    bias_cat_k<<<1, 128, 0, stream>>>(boff, ba, b_oa);

    cvt_k<<<(RTOT*CC/4 + 255) / 256, 256, 0, stream>>>(value, val_b, RTOT*CC/4);
    ln_k<<<RTOT / 4, 256, 0, stream>>>(x, ln1w, ln1b, xn_b);

    dim3 blk(256);
    gemm_t<0, false><<<dim3(RTOT/128, 2), blk, 0, stream>>>(val_b, wt_v,  bv,   nullptr, v_b,  RTOT, 256,  256);
    gemm_t<0, false><<<dim3(RTOT/128, 1), blk, 0, stream>>>(xn_b,  wt_oa, b_oa, nullptr, oa_b, RTOT, 96,   256);
    sample_k<<<RTOT / 8, 256, 0, stream>>>(v_b, ref, oa_b, smp_b);
    gemm_t<2, true ><<<dim3(RTOT/128, 2), blk, 0, stream>>>(smp_b, wt_o,  bout, x,       x2_f, RTOT, 256,  256);
    ln_k<<<RTOT / 4, 256, 0, stream>>>(x2_f, ln2w, ln2b, h_b);
    // fused MLP: out = x2 + gelu(h@W1+b1)@W2 + b2
    mlp_k<<<RTOT / 64, blk, 0, stream>>>(h_b, w1s_b, b1, w2s_b, b2, x2_f, (float*)d_out);
}